// Round 3
// baseline (1088.332 us; speedup 1.0000x reference)
//
#include <hip/hip_runtime.h>
#include <math.h>

#define HH 128      // hidden
#define DD 2048     // input size
#define BATCH 64
#define TT 256
#define G4 512      // 4*H
#define GB 16       // batches per recurrence block
#define HPAD 136    // padded h row length (halves); 272B rows -> 2-way banks max

typedef __attribute__((ext_vector_type(8))) short bf16x8;   // 8 bf16
typedef __attribute__((ext_vector_type(4))) float f32x4;
typedef _Float16 f16x8 __attribute__((ext_vector_type(8))); // 8 fp16

// ---- helpers ---------------------------------------------------------------
static __device__ __forceinline__ unsigned short f2bf_rne(float f) {
    union { float f; unsigned u; } v; v.f = f;
    unsigned r = v.u + 0x7fff + ((v.u >> 16) & 1);
    return (unsigned short)(r >> 16);
}
static __device__ __forceinline__ float bf2f(unsigned short b) {
    union { unsigned u; float f; } v; v.u = ((unsigned)b) << 16;
    return v.f;
}
static __device__ __forceinline__ float fexp2(float x) {
#if __has_builtin(__builtin_amdgcn_exp2f)
    return __builtin_amdgcn_exp2f(x);
#else
    return exp2f(x);
#endif
}
static __device__ __forceinline__ float frcp(float x) {
#if __has_builtin(__builtin_amdgcn_rcpf)
    return __builtin_amdgcn_rcpf(x);
#else
    return 1.f / x;
#endif
}
static __device__ __forceinline__ float sigmoid_f(float x) {
    return frcp(1.f + fexp2(-1.44269504f * x));
}
static __device__ __forceinline__ float tanh_f(float x) {
    float xx = fminf(fmaxf(x, -15.f), 15.f);
    float e = fexp2(2.88539008f * xx);               // exp(2x)
    return 1.f - 2.f * frcp(e + 1.f);
}

// ---------------------------------------------------------------------------
// Split-bf16 GEMM: C[M,Nperm] = A[M,K] @ Bperm[N,K]^T + bias[orig(n)]
// PERMUTED N: output column n' = 4u+g holds original gate row g*128+u, so the
// recurrence kernel sees the 4 gates of unit u at consecutive columns.
// 128x128 tile, BK=32, 256 threads = 4 waves (2x2), 3-pass split-bf16 MFMA.
// ---------------------------------------------------------------------------
#define PK 40   // LDS row stride in halves (80 B)

__global__ __launch_bounds__(256) void gemm_split_bf16(
    const float* __restrict__ A, const float* __restrict__ Bw,
    const float* __restrict__ b1, const float* __restrict__ b2,
    float* __restrict__ C, int M, int N, int K)
{
    __shared__ unsigned short Ah[128 * PK], Al[128 * PK];
    __shared__ unsigned short Bh[128 * PK], Bl[128 * PK];

    const int tid = threadIdx.x;
    const int l = tid & 63;
    const int w = tid >> 6;
    const int wr = w >> 1, wc = w & 1;
    const int bm = blockIdx.y, bn = blockIdx.x;

    f32x4 acc[4][4];
#pragma unroll
    for (int m = 0; m < 4; ++m)
#pragma unroll
        for (int n = 0; n < 4; ++n) acc[m][n] = f32x4{0.f, 0.f, 0.f, 0.f};

    const float* Ab = A + (size_t)(bm * 128) * K;

    for (int k0 = 0; k0 < K; k0 += 32) {
        __syncthreads();
#pragma unroll
        for (int q = 0; q < 4; ++q) {
            int fid = tid + 256 * q;
            int r = fid >> 3;
            int kk = (fid & 7) << 2;
            // B row permutation: tile row r -> global n -> original weight row
            int n = bn * 128 + r;
            int orign = ((n & 3) << 7) | (n >> 2);
            float4 av = *(const float4*)(Ab + (size_t)r * K + k0 + kk);
            float4 bv = *(const float4*)(Bw + (size_t)orign * K + k0 + kk);
            float a4[4] = {av.x, av.y, av.z, av.w};
            float b4[4] = {bv.x, bv.y, bv.z, bv.w};
            ushort4 ahv, alv, bhv, blv;
            unsigned short t;
            t = f2bf_rne(a4[0]); ahv.x = t; alv.x = f2bf_rne(a4[0] - bf2f(t));
            t = f2bf_rne(a4[1]); ahv.y = t; alv.y = f2bf_rne(a4[1] - bf2f(t));
            t = f2bf_rne(a4[2]); ahv.z = t; alv.z = f2bf_rne(a4[2] - bf2f(t));
            t = f2bf_rne(a4[3]); ahv.w = t; alv.w = f2bf_rne(a4[3] - bf2f(t));
            t = f2bf_rne(b4[0]); bhv.x = t; blv.x = f2bf_rne(b4[0] - bf2f(t));
            t = f2bf_rne(b4[1]); bhv.y = t; blv.y = f2bf_rne(b4[1] - bf2f(t));
            t = f2bf_rne(b4[2]); bhv.z = t; blv.z = f2bf_rne(b4[2] - bf2f(t));
            t = f2bf_rne(b4[3]); bhv.w = t; blv.w = f2bf_rne(b4[3] - bf2f(t));
            int off = r * PK + kk;
            *(ushort4*)&Ah[off] = ahv;
            *(ushort4*)&Al[off] = alv;
            *(ushort4*)&Bh[off] = bhv;
            *(ushort4*)&Bl[off] = blv;
        }
        __syncthreads();

        bf16x8 aH[4], aL[4], bH[4], bL[4];
#pragma unroll
        for (int m = 0; m < 4; ++m) {
            int row = wr * 64 + m * 16 + (l & 15);
            int off = row * PK + 8 * (l >> 4);
            aH[m] = *(const bf16x8*)&Ah[off];
            aL[m] = *(const bf16x8*)&Al[off];
        }
#pragma unroll
        for (int n = 0; n < 4; ++n) {
            int row = wc * 64 + n * 16 + (l & 15);
            int off = row * PK + 8 * (l >> 4);
            bH[n] = *(const bf16x8*)&Bh[off];
            bL[n] = *(const bf16x8*)&Bl[off];
        }
#pragma unroll
        for (int m = 0; m < 4; ++m)
#pragma unroll
            for (int n = 0; n < 4; ++n) {
                acc[m][n] = __builtin_amdgcn_mfma_f32_16x16x32_bf16(aH[m], bH[n], acc[m][n], 0, 0, 0);
                acc[m][n] = __builtin_amdgcn_mfma_f32_16x16x32_bf16(aH[m], bL[n], acc[m][n], 0, 0, 0);
                acc[m][n] = __builtin_amdgcn_mfma_f32_16x16x32_bf16(aL[m], bH[n], acc[m][n], 0, 0, 0);
            }
    }

#pragma unroll
    for (int n = 0; n < 4; ++n) {
        int cg = bn * 128 + wc * 64 + n * 16 + (l & 15);
        int orig = ((cg & 3) << 7) | (cg >> 2);
        float bias = b1[orig] + b2[orig];
#pragma unroll
        for (int m = 0; m < 4; ++m) {
            int r0 = bm * 128 + wr * 64 + m * 16 + ((l >> 4) << 2);
            f32x4 v = acc[m][n];
#pragma unroll
            for (int i = 0; i < 4; ++i)
                C[(size_t)(r0 + i) * N + cg] = v[i] + bias;
        }
    }
}

// ---------------------------------------------------------------------------
// MFMA LSTM recurrence. 4 blocks x 16 batches, 512 threads (8 waves).
// Per step computes gates^T[512,16] = Whh_perm[512,128] @ h^T[128,16] via
// f16 MFMA 16x16x32: A = Whh fragments resident in VGPRs (perm row = 4u+g),
// B = h tile in LDS ([16][HPAD] fp16, double-buffered, b128 frag reads),
// C init = xp (prefetched f32). C/D layout (col=lane&15=batch,
// row=(lane>>4)*4+i) puts gates i,f,g,o of unit u = 4*mt+(lane>>4) into one
// lane's f32x4 -> activations + c,h update fully lane-local, 1 barrier/step.
// ---------------------------------------------------------------------------
template <bool WRITE_SEQ, bool FINAL_FC>
__global__ __launch_bounds__(512) void lstm_rec_mfma(
    const float* __restrict__ xp,    // [64,256,512] permuted gate columns
    const float* __restrict__ Whh,   // [512,128] fp32 original layout
    float* __restrict__ seq_out,     // [64,256,128] (WRITE_SEQ)
    const float* __restrict__ Wfc,   // [128] (FINAL_FC)
    const float* __restrict__ bfc,   // [1]
    float* __restrict__ out)         // [64]
{
    const int tid = threadIdx.x;
    const int l  = tid & 63;
    const int w  = tid >> 6;     // wave 0..7 -> m-tiles 4w..4w+3 (units 16w..16w+15)
    const int lb = l & 15;       // batch lane / A-frag row
    const int lg = l >> 4;       // 0..3
    const int b  = blockIdx.x * GB + lb;

    __shared__ ushort hbuf[2][GB][HPAD];
    __shared__ float red[8][GB];

    for (int i = tid; i < 2 * GB * HPAD; i += 512) ((ushort*)hbuf)[i] = 0;

    // ---- stage Whh as A-fragments (fp16), gate-interleaved permutation ----
    f16x8 wf[4][4];                    // [mm][kt]
#pragma unroll
    for (int mm = 0; mm < 4; ++mm) {
        int rp = (w * 4 + mm) * 16 + lb;             // permuted gate row
        int orig = ((rp & 3) << 7) | (rp >> 2);      // = g*128 + u
        const float* wr_ = Whh + (size_t)orig * HH;
#pragma unroll
        for (int kt = 0; kt < 4; ++kt) {
            float4 x0 = *(const float4*)(wr_ + kt * 32 + lg * 8);
            float4 x1 = *(const float4*)(wr_ + kt * 32 + lg * 8 + 4);
            f16x8 f;
            f[0] = (_Float16)x0.x; f[1] = (_Float16)x0.y;
            f[2] = (_Float16)x0.z; f[3] = (_Float16)x0.w;
            f[4] = (_Float16)x1.x; f[5] = (_Float16)x1.y;
            f[6] = (_Float16)x1.z; f[7] = (_Float16)x1.w;
            wf[mm][kt] = f;
        }
    }

    const float* xpb = xp + (size_t)b * TT * G4;
    float4 xq[4];
#pragma unroll
    for (int mm = 0; mm < 4; ++mm)
        xq[mm] = *(const float4*)(xpb + (w * 64 + mm * 16) + lg * 4);

    float c4[4] = {0.f, 0.f, 0.f, 0.f};
    float hv[4] = {0.f, 0.f, 0.f, 0.f};
    __syncthreads();

    int cur = 0;
    for (int t = 0; t < TT; ++t) {
        // B fragments: h[batch=lb][units kt*32 + lg*8 .. +7]
        f16x8 bf[4];
#pragma unroll
        for (int kt = 0; kt < 4; ++kt) {
            union { uint4 u; f16x8 h; } cvt;
            cvt.u = *(const uint4*)&hbuf[cur][lb][kt * 32 + lg * 8];
            bf[kt] = cvt.h;
        }
        // prefetch next step's xp
        int tn = (t + 1 < TT) ? t + 1 : t;
        float4 xn[4];
#pragma unroll
        for (int mm = 0; mm < 4; ++mm)
            xn[mm] = *(const float4*)(xpb + (size_t)tn * G4 + w * 64 + mm * 16 + lg * 4);

        f32x4 acc[4];
#pragma unroll
        for (int mm = 0; mm < 4; ++mm)
            acc[mm] = f32x4{xq[mm].x, xq[mm].y, xq[mm].z, xq[mm].w};
#pragma unroll
        for (int kt = 0; kt < 4; ++kt)
#pragma unroll
            for (int mm = 0; mm < 4; ++mm)
                acc[mm] = __builtin_amdgcn_mfma_f32_16x16x32_f16(wf[mm][kt], bf[kt], acc[mm], 0, 0, 0);

#pragma unroll
        for (int mm = 0; mm < 4; ++mm) {
            float iv = sigmoid_f(acc[mm][0]);
            float fv = sigmoid_f(acc[mm][1]);
            float gg = tanh_f(acc[mm][2]);
            float ov = sigmoid_f(acc[mm][3]);
            float c = fmaf(fv, c4[mm], iv * gg);
            c4[mm] = c;
            float h = ov * tanh_f(c);
            hv[mm] = h;
            int u = (w * 4 + mm) * 4 + lg;
            union { _Float16 f; ushort s; } hc; hc.f = (_Float16)h;
            hbuf[cur ^ 1][lb][u] = hc.s;
            if (WRITE_SEQ)
                seq_out[((size_t)b * TT + t) * HH + u] = h;
        }
        __syncthreads();
        cur ^= 1;
#pragma unroll
        for (int mm = 0; mm < 4; ++mm) xq[mm] = xn[mm];
    }

    if (FINAL_FC) {
        float p = 0.f;
#pragma unroll
        for (int mm = 0; mm < 4; ++mm) {
            int u = (w * 4 + mm) * 4 + lg;
            p = fmaf(hv[mm], Wfc[u], p);
        }
        p += __shfl_xor(p, 16, 64);
        p += __shfl_xor(p, 32, 64);
        if (l < GB) red[w][l] = p;
        __syncthreads();
        if (tid < GB) {
            float s = bfc[0];
#pragma unroll
            for (int q = 0; q < 8; ++q) s += red[q][tid];
            out[blockIdx.x * GB + tid] = s;
        }
    }
}

// ---------------------------------------------------------------------------
extern "C" void kernel_launch(void* const* d_in, const int* in_sizes, int n_in,
                              void* d_out, int out_size, void* d_ws, size_t ws_size,
                              hipStream_t stream)
{
    const float* x    = (const float*)d_in[0];
    const float* Wih0 = (const float*)d_in[1];
    const float* Whh0 = (const float*)d_in[2];
    const float* bih0 = (const float*)d_in[3];
    const float* bhh0 = (const float*)d_in[4];
    const float* Wih1 = (const float*)d_in[5];
    const float* Whh1 = (const float*)d_in[6];
    const float* bih1 = (const float*)d_in[7];
    const float* bhh1 = (const float*)d_in[8];
    const float* Wfc  = (const float*)d_in[9];
    const float* bfc  = (const float*)d_in[10];
    float* out = (float*)d_out;

    const int M = BATCH * TT;              // 16384
    float* xp  = (float*)d_ws;             // [16384,512] (permuted gate cols)
    float* seq = xp + (size_t)M * G4;      // [16384,128]

    // 1) xp0 = x @ Wih0_perm^T + biases (permuted)
    gemm_split_bf16<<<dim3(G4 / 128, M / 128), 256, 0, stream>>>(
        x, Wih0, bih0, bhh0, xp, M, G4, DD);

    // 2) layer-0 recurrence (MFMA) -> seq
    lstm_rec_mfma<true, false><<<BATCH / GB, 512, 0, stream>>>(
        xp, Whh0, seq, nullptr, nullptr, nullptr);

    // 3) xp1 = seq @ Wih1_perm^T + biases (permuted)
    gemm_split_bf16<<<dim3(G4 / 128, M / 128), 256, 0, stream>>>(
        seq, Wih1, bih1, bhh1, xp, M, G4, HH);

    // 4) layer-1 recurrence (MFMA) + fused FC head
    lstm_rec_mfma<false, true><<<BATCH / GB, 512, 0, stream>>>(
        xp, Whh1, nullptr, Wfc, bfc, out);
}

// Round 4
// 868.579 us; speedup vs baseline: 1.2530x; 1.2530x over previous
//
#include <hip/hip_runtime.h>
#include <math.h>

#define HH 128      // hidden
#define DD 2048     // input size
#define BATCH 64
#define TT 256
#define G4 512      // 4*H
#define GB 16       // batches per recurrence block (4 blocks)
#define HPAD 136    // padded h row length (halves)

typedef __attribute__((ext_vector_type(8))) short bf16x8;   // 8 bf16
typedef __attribute__((ext_vector_type(4))) float f32x4;
typedef _Float16 f16x8 __attribute__((ext_vector_type(8))); // 8 fp16

// xp layout (permuted for coalesced recurrence loads):
//   elem(t, b, n')  with blk=b>>4, lb=b&15, w=n'>>6, mm=(n'>>4)&3, low=n'&15
//   addr = t*32768 + blk*8192 + w*1024 + mm*256 + lb*16 + low
// Recurrence lane (w, lg=l>>4, lb=l&15) reads float4 at ... + lg*4 -> wave
// covers 1KB contiguous per (w,mm). GEMM epilogue writes 64B contiguous per
// 16-lane group (low = cg&15 spans 0..15).

// ---- helpers ---------------------------------------------------------------
static __device__ __forceinline__ unsigned short f2bf_rne(float f) {
    union { float f; unsigned u; } v; v.f = f;
    unsigned r = v.u + 0x7fff + ((v.u >> 16) & 1);
    return (unsigned short)(r >> 16);
}
static __device__ __forceinline__ float bf2f(unsigned short b) {
    union { unsigned u; float f; } v; v.u = ((unsigned)b) << 16;
    return v.f;
}
static __device__ __forceinline__ float fexp2(float x) {
#if __has_builtin(__builtin_amdgcn_exp2f)
    return __builtin_amdgcn_exp2f(x);
#else
    return exp2f(x);
#endif
}
static __device__ __forceinline__ float frcp(float x) {
#if __has_builtin(__builtin_amdgcn_rcpf)
    return __builtin_amdgcn_rcpf(x);
#else
    return 1.f / x;
#endif
}
static __device__ __forceinline__ float sigmoid_f(float x) {
    return frcp(1.f + fexp2(-1.44269504f * x));
}
static __device__ __forceinline__ float tanh_f(float x) {
    float xx = fminf(fmaxf(x, -15.f), 15.f);
    float e = fexp2(2.88539008f * xx);               // exp(2x)
    return 1.f - 2.f * frcp(e + 1.f);
}

// ---------------------------------------------------------------------------
// Split-bf16 GEMM: xp(t,b,n') = A[M,K] @ Bperm[N,K]^T + bias, permuted output.
// N permutation: col n' = 4u+g holds original gate row g*128+u.
// 128x128 tile, BK=32, 256 threads = 4 waves (2x2), 3-pass split-bf16 MFMA.
// ---------------------------------------------------------------------------
#define PK 40   // LDS row stride in halves (80 B)

__global__ __launch_bounds__(256) void gemm_split_bf16(
    const float* __restrict__ A, const float* __restrict__ Bw,
    const float* __restrict__ b1, const float* __restrict__ b2,
    float* __restrict__ C, int M, int N, int K)
{
    __shared__ unsigned short Ah[128 * PK], Al[128 * PK];
    __shared__ unsigned short Bh[128 * PK], Bl[128 * PK];

    const int tid = threadIdx.x;
    const int l = tid & 63;
    const int w = tid >> 6;
    const int wr = w >> 1, wc = w & 1;
    const int bm = blockIdx.y, bn = blockIdx.x;

    f32x4 acc[4][4];
#pragma unroll
    for (int m = 0; m < 4; ++m)
#pragma unroll
        for (int n = 0; n < 4; ++n) acc[m][n] = f32x4{0.f, 0.f, 0.f, 0.f};

    const float* Ab = A + (size_t)(bm * 128) * K;

    for (int k0 = 0; k0 < K; k0 += 32) {
        __syncthreads();
#pragma unroll
        for (int q = 0; q < 4; ++q) {
            int fid = tid + 256 * q;
            int r = fid >> 3;
            int kk = (fid & 7) << 2;
            int n = bn * 128 + r;
            int orign = ((n & 3) << 7) | (n >> 2);
            float4 av = *(const float4*)(Ab + (size_t)r * K + k0 + kk);
            float4 bv = *(const float4*)(Bw + (size_t)orign * K + k0 + kk);
            float a4[4] = {av.x, av.y, av.z, av.w};
            float b4[4] = {bv.x, bv.y, bv.z, bv.w};
            ushort4 ahv, alv, bhv, blv;
            unsigned short t;
            t = f2bf_rne(a4[0]); ahv.x = t; alv.x = f2bf_rne(a4[0] - bf2f(t));
            t = f2bf_rne(a4[1]); ahv.y = t; alv.y = f2bf_rne(a4[1] - bf2f(t));
            t = f2bf_rne(a4[2]); ahv.z = t; alv.z = f2bf_rne(a4[2] - bf2f(t));
            t = f2bf_rne(a4[3]); ahv.w = t; alv.w = f2bf_rne(a4[3] - bf2f(t));
            t = f2bf_rne(b4[0]); bhv.x = t; blv.x = f2bf_rne(b4[0] - bf2f(t));
            t = f2bf_rne(b4[1]); bhv.y = t; blv.y = f2bf_rne(b4[1] - bf2f(t));
            t = f2bf_rne(b4[2]); bhv.z = t; blv.z = f2bf_rne(b4[2] - bf2f(t));
            t = f2bf_rne(b4[3]); bhv.w = t; blv.w = f2bf_rne(b4[3] - bf2f(t));
            int off = r * PK + kk;
            *(ushort4*)&Ah[off] = ahv;
            *(ushort4*)&Al[off] = alv;
            *(ushort4*)&Bh[off] = bhv;
            *(ushort4*)&Bl[off] = blv;
        }
        __syncthreads();

        bf16x8 aH[4], aL[4], bH[4], bL[4];
#pragma unroll
        for (int m = 0; m < 4; ++m) {
            int row = wr * 64 + m * 16 + (l & 15);
            int off = row * PK + 8 * (l >> 4);
            aH[m] = *(const bf16x8*)&Ah[off];
            aL[m] = *(const bf16x8*)&Al[off];
        }
#pragma unroll
        for (int n = 0; n < 4; ++n) {
            int row = wc * 64 + n * 16 + (l & 15);
            int off = row * PK + 8 * (l >> 4);
            bH[n] = *(const bf16x8*)&Bh[off];
            bL[n] = *(const bf16x8*)&Bl[off];
        }
#pragma unroll
        for (int m = 0; m < 4; ++m)
#pragma unroll
            for (int n = 0; n < 4; ++n) {
                acc[m][n] = __builtin_amdgcn_mfma_f32_16x16x32_bf16(aH[m], bH[n], acc[m][n], 0, 0, 0);
                acc[m][n] = __builtin_amdgcn_mfma_f32_16x16x32_bf16(aH[m], bL[n], acc[m][n], 0, 0, 0);
                acc[m][n] = __builtin_amdgcn_mfma_f32_16x16x32_bf16(aL[m], bH[n], acc[m][n], 0, 0, 0);
            }
    }

    // epilogue: permuted-layout scatter (64B contiguous per 16-lane group)
#pragma unroll
    for (int n = 0; n < 4; ++n) {
        int cg = bn * 128 + wc * 64 + n * 16 + (l & 15);
        int orig = ((cg & 3) << 7) | (cg >> 2);
        float bias = b1[orig] + b2[orig];
        size_t cbase = (size_t)(cg >> 6) * 1024 + ((cg >> 4) & 3) * 256 + (cg & 15);
#pragma unroll
        for (int m = 0; m < 4; ++m) {
            int r0 = bm * 128 + wr * 64 + m * 16 + ((l >> 4) << 2);
            f32x4 v = acc[m][n];
#pragma unroll
            for (int i = 0; i < 4; ++i) {
                int r = r0 + i;
                int t = r & 255, b = r >> 8;
                C[(size_t)t * 32768 + (size_t)(b >> 4) * 8192 + cbase + (b & 15) * 16] = v[i] + bias;
            }
        }
    }
}

// ---------------------------------------------------------------------------
// MFMA LSTM recurrence. 4 blocks x 16 batches, 512 threads (8 waves).
// gates^T[512,16] = Whh_perm[512,128] @ h^T[128,16] via f16 MFMA 16x16x32.
// A = Whh fragments in VGPRs; B = h in LDS (double-buffered, 1 barrier/step);
// C init = xp from the permuted coalesced layout, prefetched 2 steps deep
// (2x-unrolled loop, alternating X0/X1 register sets -> no copy waits).
// ---------------------------------------------------------------------------
template <bool WRITE_SEQ, bool FINAL_FC>
__global__ __launch_bounds__(512, 1) void lstm_rec_mfma(
    const float* __restrict__ xp,    // permuted layout, see top comment
    const float* __restrict__ Whh,   // [512,128] fp32 original layout
    float* __restrict__ seq_out,     // [64,256,128] (WRITE_SEQ)
    const float* __restrict__ Wfc,   // [128] (FINAL_FC)
    const float* __restrict__ bfc,   // [1]
    float* __restrict__ out)         // [64]
{
    const int tid = threadIdx.x;
    const int l  = tid & 63;
    const int w  = tid >> 6;     // wave 0..7
    const int lb = l & 15;       // batch lane / C col
    const int lg = l >> 4;       // 0..3
    const int blk = blockIdx.x;

    __shared__ ushort hbuf[2][GB][HPAD];
    __shared__ float red[8][GB];

    for (int i = tid; i < 2 * GB * HPAD; i += 512) ((ushort*)hbuf)[i] = 0;

    // ---- Whh A-fragments (fp16), gate-interleaved permutation -------------
    f16x8 wf[4][4];                    // [mm][kt]
#pragma unroll
    for (int mm = 0; mm < 4; ++mm) {
        int rp = (w * 4 + mm) * 16 + lb;             // permuted gate row
        int orig = ((rp & 3) << 7) | (rp >> 2);      // = g*128 + u
        const float* wr_ = Whh + (size_t)orig * HH;
#pragma unroll
        for (int kt = 0; kt < 4; ++kt) {
            float4 x0 = *(const float4*)(wr_ + kt * 32 + lg * 8);
            float4 x1 = *(const float4*)(wr_ + kt * 32 + lg * 8 + 4);
            f16x8 f;
            f[0] = (_Float16)x0.x; f[1] = (_Float16)x0.y;
            f[2] = (_Float16)x0.z; f[3] = (_Float16)x0.w;
            f[4] = (_Float16)x1.x; f[5] = (_Float16)x1.y;
            f[6] = (_Float16)x1.z; f[7] = (_Float16)x1.w;
            wf[mm][kt] = f;
        }
    }

    const float* xbase = xp + (size_t)blk * 8192 + w * 1024 + lb * 16 + lg * 4;
    float4 X0[4], X1[4];
#pragma unroll
    for (int mm = 0; mm < 4; ++mm) X0[mm] = *(const float4*)(xbase + mm * 256);
#pragma unroll
    for (int mm = 0; mm < 4; ++mm) X1[mm] = *(const float4*)(xbase + 32768 + mm * 256);

    float c4[4] = {0.f, 0.f, 0.f, 0.f};
    float hv[4] = {0.f, 0.f, 0.f, 0.f};
    int cur = 0;
    __syncthreads();

    auto step = [&](int t, float4* X, int tp) {
        // B fragments from current h buffer
        f16x8 bfr[4];
#pragma unroll
        for (int kt = 0; kt < 4; ++kt) {
            union { uint4 u; f16x8 h; } cvt;
            cvt.u = *(const uint4*)&hbuf[cur][lb][kt * 32 + lg * 8];
            bfr[kt] = cvt.h;
        }
        // init acc from prefetched xp, then immediately issue load for t+2
        f32x4 acc[4];
#pragma unroll
        for (int mm = 0; mm < 4; ++mm)
            acc[mm] = f32x4{X[mm].x, X[mm].y, X[mm].z, X[mm].w};
        const float* pp = xbase + (size_t)tp * 32768;
#pragma unroll
        for (int mm = 0; mm < 4; ++mm) X[mm] = *(const float4*)(pp + mm * 256);

#pragma unroll
        for (int kt = 0; kt < 4; ++kt)
#pragma unroll
            for (int mm = 0; mm < 4; ++mm)
                acc[mm] = __builtin_amdgcn_mfma_f32_16x16x32_f16(wf[mm][kt], bfr[kt], acc[mm], 0, 0, 0);

#pragma unroll
        for (int mm = 0; mm < 4; ++mm) {
            float iv = sigmoid_f(acc[mm][0]);
            float fv = sigmoid_f(acc[mm][1]);
            float gg = tanh_f(acc[mm][2]);
            float ov = sigmoid_f(acc[mm][3]);
            float c = fmaf(fv, c4[mm], iv * gg);
            c4[mm] = c;
            float h = ov * tanh_f(c);
            hv[mm] = h;
            int u = (w * 4 + mm) * 4 + lg;
            union { _Float16 f; ushort s; } hc; hc.f = (_Float16)h;
            hbuf[cur ^ 1][lb][u] = hc.s;
            if (WRITE_SEQ)
                seq_out[((size_t)(blk * GB + lb) * TT + t) * HH + u] = h;
        }
        __syncthreads();
        cur ^= 1;
    };

    for (int t = 0; t < TT; t += 2) {
        int tp0 = (t + 2 < TT) ? t + 2 : TT - 1;
        int tp1 = (t + 3 < TT) ? t + 3 : TT - 1;
        step(t,     X0, tp0);
        step(t + 1, X1, tp1);
    }

    if (FINAL_FC) {
        float p = 0.f;
#pragma unroll
        for (int mm = 0; mm < 4; ++mm) {
            int u = (w * 4 + mm) * 4 + lg;
            p = fmaf(hv[mm], Wfc[u], p);
        }
        p += __shfl_xor(p, 16, 64);
        p += __shfl_xor(p, 32, 64);
        if (l < GB) red[w][l] = p;
        __syncthreads();
        if (tid < GB) {
            float s = bfc[0];
#pragma unroll
            for (int q = 0; q < 8; ++q) s += red[q][tid];
            out[blk * GB + tid] = s;
        }
    }
}

// ---------------------------------------------------------------------------
extern "C" void kernel_launch(void* const* d_in, const int* in_sizes, int n_in,
                              void* d_out, int out_size, void* d_ws, size_t ws_size,
                              hipStream_t stream)
{
    const float* x    = (const float*)d_in[0];
    const float* Wih0 = (const float*)d_in[1];
    const float* Whh0 = (const float*)d_in[2];
    const float* bih0 = (const float*)d_in[3];
    const float* bhh0 = (const float*)d_in[4];
    const float* Wih1 = (const float*)d_in[5];
    const float* Whh1 = (const float*)d_in[6];
    const float* bih1 = (const float*)d_in[7];
    const float* bhh1 = (const float*)d_in[8];
    const float* Wfc  = (const float*)d_in[9];
    const float* bfc  = (const float*)d_in[10];
    float* out = (float*)d_out;

    const int M = BATCH * TT;              // 16384
    float* xp  = (float*)d_ws;             // [8.4M floats] permuted layout
    float* seq = xp + (size_t)M * G4;      // [16384,128] row-major

    // 1) xp0 = x @ Wih0_perm^T + biases -> permuted layout
    gemm_split_bf16<<<dim3(G4 / 128, M / 128), 256, 0, stream>>>(
        x, Wih0, bih0, bhh0, xp, M, G4, DD);

    // 2) layer-0 recurrence (MFMA) -> seq
    lstm_rec_mfma<true, false><<<BATCH / GB, 512, 0, stream>>>(
        xp, Whh0, seq, nullptr, nullptr, nullptr);

    // 3) xp1 = seq @ Wih1_perm^T + biases -> permuted layout
    gemm_split_bf16<<<dim3(G4 / 128, M / 128), 256, 0, stream>>>(
        seq, Wih1, bih1, bhh1, xp, M, G4, HH);

    // 4) layer-1 recurrence (MFMA) + fused FC head
    lstm_rec_mfma<false, true><<<BATCH / GB, 512, 0, stream>>>(
        xp, Whh1, nullptr, Wfc, bfc, out);
}